// Round 5
// baseline (1322.615 us; speedup 1.0000x reference)
//
#include <hip/hip_runtime.h>
#include <stdint.h>

constexpr int B = 512, S = 1024, IN = 32, H = 128;
constexpr int KTOT = IN + H;    // 160
constexpr int NJ = 4;           // k-slices (wave-uniform)
constexpr int KSL = KTOT / NJ;  // 40 k per slice
constexpr int KP = KSL / 2;     // 20 half2 pairs

typedef uint32_t u32;

// D = a.h0*b.h0 + a.h1*b.h1 + D  (fp16 inputs, fp32 accumulate)
__device__ __forceinline__ void dot2(float& c, u32 a, u32 b) {
  asm("v_dot2_f32_f16 %0, %1, %2, %0" : "+v"(c) : "v"(a), "v"(b));
}
__device__ __forceinline__ float sigm(float v) {
  float e = __builtin_amdgcn_exp2f(-1.4426950408889634f * v);
  return __builtin_amdgcn_rcpf(1.0f + e);
}
__device__ __forceinline__ float tanh_(float v) {
  float e = __builtin_amdgcn_exp2f(-2.8853900817779268f * v);
  return 2.0f * __builtin_amdgcn_rcpf(1.0f + e) - 1.0f;
}

// Exactly 4 waves/EU (min AND max): VGPR cap 128, and no incentive for the
// allocator to squeeze to the 8-wave/64-VGPR boundary (round-4 spill bug).
__global__ __attribute__((amdgpu_flat_work_group_size(512, 512)))
__attribute__((amdgpu_waves_per_eu(4, 4)))
void lstm_fused(const float* __restrict__ x, const float* __restrict__ Wih,
                const float* __restrict__ Whh, const float* __restrict__ bih,
                const float* __restrict__ bhh, const float* __restrict__ Wlin,
                const float* __restrict__ blin, float* __restrict__ out) {
  __shared__ alignas(16) _Float16 hx[2][KTOT];  // ping-pong [x(32)|h(128)], fp16
  __shared__ alignas(16) float red[NJ][H][4];   // per-slice partials [j][g][gate]
  __shared__ float redf[H];

  const int tid = threadIdx.x;
  const int lane = tid & 63;
  const int w = tid >> 6;             // wave 0..7
  const int j = w >> 1;               // k-slice, wave-uniform
  const int g = (w & 1) * 64 + lane;  // gate-row this thread dots for
  const int b = blockIdx.x;           // one batch row per block
  const int par = b & 1;
  const int aw0 = par, aw1 = 6 + par; // act waves (stagger SIMDs by block parity)
  const bool isact = (w == aw0) || (w == aw1);
  const int ga = (w == aw0) ? lane : 64 + lane;  // act-wave's gate-row
  const int xw = 2 + par;             // x-prefetch wave

  // ---- weights -> packed half2 regs: 4 gates x 20 pairs = 80 VGPRs ----
  u32 wreg[4][KP];
#pragma unroll
  for (int c = 0; c < 4; ++c) {
    const int n = c * H + g;
#pragma unroll
    for (int pq = 0; pq < KP; ++pq) {
      const int k0 = KSL * j + 2 * pq, k1 = k0 + 1;
      const float f0 = (k0 < IN) ? Wih[n * IN + k0] : Whh[n * H + (k0 - IN)];
      const float f1 = (k1 < IN) ? Wih[n * IN + k1] : Whh[n * H + (k1 - IN)];
      union { _Float16 h[2]; u32 u; } cv;
      cv.h[0] = (_Float16)f0;
      cv.h[1] = (_Float16)f1;
      wreg[c][pq] = cv.u;
    }
  }
#pragma unroll
  for (int c = 0; c < 4; ++c)
#pragma unroll
    for (int pq = 0; pq < KP; ++pq) asm volatile("" : "+v"(wreg[c][pq]));

  float bias_a[4] = {0.f, 0.f, 0.f, 0.f};
  if (isact) {
#pragma unroll
    for (int c = 0; c < 4; ++c) bias_a[c] = bih[c * H + ga] + bhh[c * H + ga];
  }

  // ---- init: hx[0] = (x_0 | zeros); hx[1] zeroed ----
  const size_t xbase = (size_t)b * S * IN;
  if (tid < KTOT) {
    hx[0][tid] = (tid < IN) ? (_Float16)x[xbase + tid] : (_Float16)0.0f;
    hx[1][tid] = (_Float16)0.0f;
  }
  __syncthreads();

  float cc = 0.f, oa = 0.f;
  // slice base pointers hoisted out of the loop (no per-step address math)
  const uint4* const base0 = (const uint4*)((const char*)&hx[0][0] + j * (KSL * 2));
  const uint4* const base1 = (const uint4*)((const char*)&hx[1][0] + j * (KSL * 2));

  for (int s = 0; s < S; ++s) {
    const int np = (s & 1) ^ 1;
    const uint4* const pp = (s & 1) ? base1 : base0;
    float wl = 0.f;
    if (isact) wl = Wlin[s * H + ga];  // early issue; L2-resident

    // ---- dots: wave-broadcast LDS reads, consume each uint4 immediately ----
    float a0 = 0.f, a1 = 0.f, a2 = 0.f, a3 = 0.f;
#pragma unroll
    for (int q = 0; q < 5; ++q) {
      const uint4 v = pp[q];
      dot2(a0, v.x, wreg[0][4 * q + 0]);
      dot2(a1, v.x, wreg[1][4 * q + 0]);
      dot2(a2, v.x, wreg[2][4 * q + 0]);
      dot2(a3, v.x, wreg[3][4 * q + 0]);
      dot2(a0, v.y, wreg[0][4 * q + 1]);
      dot2(a1, v.y, wreg[1][4 * q + 1]);
      dot2(a2, v.y, wreg[2][4 * q + 1]);
      dot2(a3, v.y, wreg[3][4 * q + 1]);
      dot2(a0, v.z, wreg[0][4 * q + 2]);
      dot2(a1, v.z, wreg[1][4 * q + 2]);
      dot2(a2, v.z, wreg[2][4 * q + 2]);
      dot2(a3, v.z, wreg[3][4 * q + 2]);
      dot2(a0, v.w, wreg[0][4 * q + 3]);
      dot2(a1, v.w, wreg[1][4 * q + 3]);
      dot2(a2, v.w, wreg[2][4 * q + 3]);
      dot2(a3, v.w, wreg[3][4 * q + 3]);
    }
    *(float4*)&red[j][g][0] = make_float4(a0, a1, a2, a3);
    __syncthreads();  // A: partials visible

    if (isact) {
      const float4 r0 = *(const float4*)&red[0][ga][0];
      const float4 r1 = *(const float4*)&red[1][ga][0];
      const float4 r2 = *(const float4*)&red[2][ga][0];
      const float4 r3 = *(const float4*)&red[3][ga][0];
      const float gi = sigm(r0.x + r1.x + r2.x + r3.x + bias_a[0]);
      const float gf = sigm(r0.y + r1.y + r2.y + r3.y + bias_a[1]);
      const float gg = tanh_(r0.z + r1.z + r2.z + r3.z + bias_a[2]);
      const float go = sigm(r0.w + r1.w + r2.w + r3.w + bias_a[3]);
      cc = gf * cc + gi * gg;
      const float h = go * tanh_(cc);
      hx[np][IN + ga] = (_Float16)h;  // h_s for step s+1
      oa += h * wl;                   // fused output linear
    } else if ((w == xw) && (lane < IN) && (s + 1 < S)) {
      hx[np][lane] = (_Float16)x[xbase + (s + 1) * IN + lane];  // x_{s+1}
    }
    __syncthreads();  // B: hx[np] complete
  }

  // ---- final reduce of fused linear ----
  if (isact) redf[ga] = oa;
  __syncthreads();
  if (tid == 0) {
    float sum = blin[0];
    for (int k = 0; k < H; ++k) sum += redf[k];
    out[b] = sum;
  }
}

extern "C" void kernel_launch(void* const* d_in, const int* in_sizes, int n_in,
                              void* d_out, int out_size, void* d_ws, size_t ws_size,
                              hipStream_t stream) {
  const float* x    = (const float*)d_in[0];
  const float* Wih  = (const float*)d_in[1];
  const float* Whh  = (const float*)d_in[2];
  const float* bih  = (const float*)d_in[3];
  const float* bhh  = (const float*)d_in[4];
  const float* Wlin = (const float*)d_in[5];
  const float* blin = (const float*)d_in[6];
  float* outp = (float*)d_out;
  hipLaunchKernelGGL(lstm_fused, dim3(B), dim3(512), 0, stream,
                     x, Wih, Whh, bih, bhh, Wlin, blin, outp);
}